// Round 8
// baseline (978.480 us; speedup 1.0000x reference)
//
#include <hip/hip_runtime.h>

typedef unsigned short u16;
typedef __attribute__((ext_vector_type(8))) short short8;
typedef __attribute__((ext_vector_type(4))) float f32x4;

#define BATCH 256
#define N0    512
#define N1    2048
#define NIN   4096
#define TSTEPS 60

static __device__ __forceinline__ f32x4 MFMA(short8 a, short8 b, f32x4 c) {
    return __builtin_amdgcn_mfma_f32_16x16x32_bf16(a, b, c, 0, 0, 0);
}

static __device__ __forceinline__ void split1(float x, u16* __restrict__ hp, u16* __restrict__ lp) {
    unsigned bx = __float_as_uint(x);
    *hp = (u16)(bx >> 16);
    float lf = x - __uint_as_float(bx & 0xFFFF0000u);
    *lp = (u16)(__float_as_uint(lf) >> 16);
}

static __device__ __forceinline__ float clamp01(float v) {
    return fminf(fmaxf(v, 0.0f), 1.0f);
}

// Packed fragment-order index for a [R x K] operand, 16x16x32 MFMA frags.
// Tile (rt,kt) holds rows [rt*16,+16), k [kt*32,+32); lane = (row&15) | ((k>>3 & 3)<<4),
// elem j = k&7. A wave's fragment load = base + (tile*64 + lane)*8 : contiguous 1KB.
static __device__ __forceinline__ size_t apos(int row, int col, int KT) {
    return ((size_t)((row >> 4) * KT + (col >> 5)) * 64
            + (size_t)((row & 15) | (((col >> 3) & 3) << 4))) * 8 + (col & 7);
}

// Dest-order pack: thread g produces packed elems [g*8, g*8+8) of dsth/dstl.
// Wave writes 2x1KB contiguous; wave reads 16 rows x 128B contiguous.
static __device__ __forceinline__ void pack_tiles(
    const float* __restrict__ src, u16* __restrict__ dsth, u16* __restrict__ dstl,
    int n8, int ktlog, int K, int tid, int nth)
{
    for (int g = tid; g < n8; g += nth) {
        const int t = g >> 6, lane = g & 63;
        const int rt = t >> ktlog, kt = t & ((1 << ktlog) - 1);
        const int row = rt * 16 + (lane & 15);
        const int col = kt * 32 + ((lane >> 4) << 3);
        const float* s = src + (size_t)row * K + col;
        const float4 x0 = *(const float4*)s;
        const float4 x1 = *(const float4*)(s + 4);
        float xs[8] = {x0.x, x0.y, x0.z, x0.w, x1.x, x1.y, x1.z, x1.w};
        union { short8 v; unsigned u[4]; } H, L;
        #pragma unroll
        for (int j = 0; j < 4; ++j) {
            unsigned ba = __float_as_uint(xs[2*j]);
            unsigned bb = __float_as_uint(xs[2*j+1]);
            H.u[j] = (ba >> 16) | (bb & 0xFFFF0000u);
            float la = xs[2*j]   - __uint_as_float(ba & 0xFFFF0000u);
            float lb = xs[2*j+1] - __uint_as_float(bb & 0xFFFF0000u);
            L.u[j] = (__float_as_uint(la) >> 16) | (__float_as_uint(lb) & 0xFFFF0000u);
        }
        *(short8*)(dsth + (size_t)g * 8) = H.v;
        *(short8*)(dstl + (size_t)g * 8) = L.v;
    }
}

// -------- prep: split + fragment-pack (dest-ordered, coalesced writes) --------
__global__ __launch_bounds__(256) void prep_kernel(
    const float* __restrict__ w0, const float* __restrict__ w1,
    const float* __restrict__ w2, const float* __restrict__ data,
    const float* __restrict__ s0, const float* __restrict__ s1,
    u16* __restrict__ w0h, u16* __restrict__ w0l,
    u16* __restrict__ w1h, u16* __restrict__ w1l,
    u16* __restrict__ w2h, u16* __restrict__ w2l,
    u16* __restrict__ dh,  u16* __restrict__ dl,
    float* __restrict__ s0f, float* __restrict__ s1f,
    u16* __restrict__ s0h, u16* __restrict__ s0l,
    u16* __restrict__ s1h, u16* __restrict__ s1l)
{
    const int tid = blockIdx.x * 256 + threadIdx.x;
    const int nth = gridDim.x * 256;
    pack_tiles(w0,   w0h, w0l, N0 * N1 / 8,        6, N1,  tid, nth);  // [512 x 2048] KT=64
    pack_tiles(w1,   w1h, w1l, N1 * N0 / 8,        4, N0,  tid, nth);  // [2048 x 512] KT=16
    pack_tiles(w2,   w2h, w2l, N1 * NIN / 8,       7, NIN, tid, nth);  // [2048 x 4096] KT=128
    pack_tiles(data, dh,  dl,  BATCH * NIN / 8,    7, NIN, tid, nth);  // [256 x 4096] KT=128
    pack_tiles(s0,   s0h, s0l, BATCH * N0 / 8,     4, N0,  tid, nth);  // [256 x 512] KT=16
    pack_tiles(s1,   s1h, s1l, BATCH * N1 / 8,     6, N1,  tid, nth);  // [256 x 2048] KT=64
    for (int i = tid; i < BATCH * N0 / 4; i += nth)
        ((float4*)s0f)[i] = ((const float4*)s0)[i];
    for (int i = tid; i < BATCH * N1 / 4; i += nth)
        ((float4*)s1f)[i] = ((const float4*)s1)[i];
}

// -------- inp1 partials: data @ w2^T --------
// 512 WGs x 8 waves: b = chunk(4) x mt(4) x nt(32). Tile 64x64, K-chunk 1024.
// Wave = 16 rows x 32 cols (2 n-frags). XCD: b%8 == nt%8 (w2 slice locality).
__global__ __launch_bounds__(512, 2) void inp1_kernel(
    const u16* __restrict__ dh, const u16* __restrict__ dl,
    const u16* __restrict__ w2h, const u16* __restrict__ w2l,
    float* __restrict__ partial)   // [4][256][2048]
{
    const int wave = threadIdx.x >> 6, lane = threadIdx.x & 63;
    const int lrow = lane & 15, lr4 = (lane >> 4) << 2;
    const int b = blockIdx.x;
    const int chunk = b >> 7, rem = b & 127;
    const int mt = rem >> 5, nt = rem & 31;
    const int wm = wave >> 1, wn = wave & 1;
    const int fm = mt * 4 + wm;
    const int fn0 = nt * 4 + wn * 2;
    const int kt0 = chunk * 32;

    const u16* pah = dh  + ((size_t)(fm  * 128 + kt0) * 64 + lane) * 8;
    const u16* pal = dl  + ((size_t)(fm  * 128 + kt0) * 64 + lane) * 8;
    const u16* pb0h = w2h + ((size_t)(fn0 * 128 + kt0) * 64 + lane) * 8;
    const u16* pb0l = w2l + ((size_t)(fn0 * 128 + kt0) * 64 + lane) * 8;
    const u16* pb1h = pb0h + (size_t)128 * 512;
    const u16* pb1l = pb0l + (size_t)128 * 512;

    f32x4 acc[2][3] = {};
    #pragma unroll 4
    for (int i = 0; i < 32; ++i) {
        const int off = i * 512;
        short8 ah = *(const short8*)(pah + off);
        short8 al = *(const short8*)(pal + off);
        short8 b0h_ = *(const short8*)(pb0h + off);
        short8 b0l_ = *(const short8*)(pb0l + off);
        short8 b1h_ = *(const short8*)(pb1h + off);
        short8 b1l_ = *(const short8*)(pb1l + off);
        acc[0][0] = MFMA(ah, b0h_, acc[0][0]);
        acc[0][1] = MFMA(ah, b0l_, acc[0][1]);
        acc[0][2] = MFMA(al, b0h_, acc[0][2]);
        acc[1][0] = MFMA(ah, b1h_, acc[1][0]);
        acc[1][1] = MFMA(ah, b1l_, acc[1][1]);
        acc[1][2] = MFMA(al, b1h_, acc[1][2]);
    }
    float* out = partial + (size_t)chunk * BATCH * N1;
    #pragma unroll
    for (int n = 0; n < 2; ++n) {
        const int col = nt * 64 + wn * 32 + n * 16 + lrow;
        #pragma unroll
        for (int r = 0; r < 4; ++r) {
            const int row = mt * 64 + wm * 16 + lr4 + r;
            out[(size_t)row * N1 + col] = acc[n][0][r] + acc[n][1][r] + acc[n][2][r];
        }
    }
}

// -------- reduce 4 partials + bias -> inp1 --------
__global__ __launch_bounds__(256) void reduce_kernel(
    const float* __restrict__ partial, const float* __restrict__ b2,
    float* __restrict__ inp1)
{
    const int e = blockIdx.x * 256 + threadIdx.x;
    const float4* p0 = (const float4*)partial;
    const float4* p1 = p0 + (BATCH * N1 / 4);
    const float4* p2 = p1 + (BATCH * N1 / 4);
    const float4* p3 = p2 + (BATCH * N1 / 4);
    const float4 b = ((const float4*)b2)[e & (N1 / 4 - 1)];
    float4 a0 = p0[e], a1 = p1[e], a2 = p2[e], a3 = p3[e];
    float4 r;
    r.x = a0.x + a1.x + a2.x + a3.x + b.x;
    r.y = a0.y + a1.y + a2.y + a3.y + b.y;
    r.z = a0.z + a1.z + a2.z + a3.z + b.z;
    r.w = a0.w + a1.w + a2.w + a3.w + b.w;
    ((float4*)inp1)[e] = r;
}

// -------- one Euler step: 256 WGs x 512 threads (8 waves) --------
// WGs 0..127  : C1 = s0 @ w1^T (K=512, no split). 64x64 tile, wave = 16x32.
//               b%8 == ng%8 -> w1 slice stays on one XCD's L2.
// WGs 128..255: C0 = s1 @ w0^T (K=2048, split 2). 32x32 tile, wave = 16x16
//               frag x K-half; 8KB LDS reduce. b%8 == ct%8.
__global__ __launch_bounds__(512, 2) void step_kernel(
    const float* __restrict__ s0f_in, const float* __restrict__ s1f_in,
    const u16* __restrict__ s0h, const u16* __restrict__ s0l,
    const u16* __restrict__ s1h, const u16* __restrict__ s1l,
    const u16* __restrict__ w0h, const u16* __restrict__ w0l,
    const u16* __restrict__ w1h, const u16* __restrict__ w1l,
    const float* __restrict__ inp1, const float* __restrict__ b0,
    float* __restrict__ s0f_out, float* __restrict__ s1f_out,
    u16* __restrict__ s0h_out, u16* __restrict__ s0l_out,
    u16* __restrict__ s1h_out, u16* __restrict__ s1l_out)
{
    __shared__ float red[2][32][32];
    const int b = blockIdx.x;
    const int wave = threadIdx.x >> 6, lane = threadIdx.x & 63;
    const int lrow = lane & 15, lr4 = (lane >> 4) << 2;
    const int tid = (int)threadIdx.x;

    if (b < 128) {
        // ---- C1: tile 64 batches x 64 n1-cols, K = 512 ----
        const int mt = b >> 5, ng = b & 31;
        const int wm = wave >> 1, wn = wave & 1;
        const int fm = mt * 4 + wm;
        const int fn0 = ng * 4 + wn * 2;
        const u16* pah = s0h + ((size_t)(fm * 16) * 64 + lane) * 8;
        const u16* pal = s0l + ((size_t)(fm * 16) * 64 + lane) * 8;
        const u16* pb0h = w1h + ((size_t)(fn0 * 16) * 64 + lane) * 8;
        const u16* pb0l = w1l + ((size_t)(fn0 * 16) * 64 + lane) * 8;
        const u16* pb1h = pb0h + (size_t)16 * 512;
        const u16* pb1l = pb0l + (size_t)16 * 512;

        f32x4 acc[2][3] = {};
        #pragma unroll 4
        for (int i = 0; i < 16; ++i) {
            const int off = i * 512;
            short8 ah = *(const short8*)(pah + off);
            short8 al = *(const short8*)(pal + off);
            short8 b0h_ = *(const short8*)(pb0h + off);
            short8 b0l_ = *(const short8*)(pb0l + off);
            short8 b1h_ = *(const short8*)(pb1h + off);
            short8 b1l_ = *(const short8*)(pb1l + off);
            acc[0][0] = MFMA(ah, b0h_, acc[0][0]);
            acc[0][1] = MFMA(ah, b0l_, acc[0][1]);
            acc[0][2] = MFMA(al, b0h_, acc[0][2]);
            acc[1][0] = MFMA(ah, b1h_, acc[1][0]);
            acc[1][1] = MFMA(ah, b1l_, acc[1][1]);
            acc[1][2] = MFMA(al, b1h_, acc[1][2]);
        }
        const int mrow = mt * 64 + wm * 16;
        #pragma unroll
        for (int n = 0; n < 2; ++n) {
            const int col = ng * 64 + wn * 32 + n * 16 + lrow;
            #pragma unroll
            for (int r = 0; r < 4; ++r) {
                const int row = mrow + lr4 + r;
                const size_t idx = (size_t)row * N1 + col;
                const float sum = acc[n][0][r] + acc[n][1][r] + acc[n][2][r];
                float v = 0.5f * (s1f_in[idx] + inp1[idx] + sum);
                v = clamp01(v);
                s1f_out[idx] = v;
                u16 h, l; split1(v, &h, &l);
                const size_t p = apos(row, col, 64);   // s1 is A of C0
                s1h_out[p] = h; s1l_out[p] = l;
            }
        }
    } else {
        // ---- C0: tile 32 batches x 32 n0-cols, K = 2048 split 2 ----
        const int local = b - 128;
        const int rt = local >> 4, ct = local & 15;
        const int kh = wave >> 2, wm = (wave >> 1) & 1, wn = wave & 1;
        const int fm = rt * 2 + wm, fn = ct * 2 + wn;
        const u16* pah = s1h + ((size_t)(fm * 64 + kh * 32) * 64 + lane) * 8;
        const u16* pal = s1l + ((size_t)(fm * 64 + kh * 32) * 64 + lane) * 8;
        const u16* pbh = w0h + ((size_t)(fn * 64 + kh * 32) * 64 + lane) * 8;
        const u16* pbl = w0l + ((size_t)(fn * 64 + kh * 32) * 64 + lane) * 8;

        f32x4 acc0 = {}, acc1 = {}, acc2 = {};
        #pragma unroll 4
        for (int i = 0; i < 32; ++i) {
            const int off = i * 512;
            short8 ah = *(const short8*)(pah + off);
            short8 al = *(const short8*)(pal + off);
            short8 bh = *(const short8*)(pbh + off);
            short8 bl = *(const short8*)(pbl + off);
            acc0 = MFMA(ah, bh, acc0);
            acc1 = MFMA(ah, bl, acc1);
            acc2 = MFMA(al, bh, acc2);
        }
        #pragma unroll
        for (int r = 0; r < 4; ++r)
            red[kh][wm * 16 + lr4 + r][wn * 16 + lrow] = acc0[r] + acc1[r] + acc2[r];
        __syncthreads();
        #pragma unroll
        for (int e = tid; e < 1024; e += 512) {
            const int r_ = e >> 5, c_ = e & 31;
            const int row = rt * 32 + r_, col = ct * 32 + c_;
            const float sum = red[0][r_][c_] + red[1][r_][c_];
            const size_t idx = (size_t)row * N0 + col;
            float v = 0.5f * (s0f_in[idx] + sum + b0[col]);
            v = clamp01(v);
            s0f_out[idx] = v;
            u16 h, l; split1(v, &h, &l);
            const size_t p = apos(row, col, 16);   // s0 is A of C1
            s0h_out[p] = h; s0l_out[p] = l;
        }
    }
}

extern "C" void kernel_launch(void* const* d_in, const int* in_sizes, int n_in,
                              void* d_out, int out_size, void* d_ws, size_t ws_size,
                              hipStream_t stream) {
    const float* data = (const float*)d_in[0];
    const float* s0_0 = (const float*)d_in[1];
    const float* s1_0 = (const float*)d_in[2];
    const float* w0   = (const float*)d_in[3];
    const float* b0   = (const float*)d_in[4];
    const float* w1   = (const float*)d_in[5];
    const float* w2   = (const float*)d_in[6];
    const float* b2   = (const float*)d_in[7];

    char* p = (char*)d_ws;
    auto alloc = [&](size_t bytes) -> char* {
        char* r = p;
        p += (bytes + 255) & ~(size_t)255;
        return r;
    };
    u16* w0h = (u16*)alloc(N0 * N1 * sizeof(u16));
    u16* w0l = (u16*)alloc(N0 * N1 * sizeof(u16));
    u16* w1h = (u16*)alloc(N0 * N1 * sizeof(u16));
    u16* w1l = (u16*)alloc(N0 * N1 * sizeof(u16));
    u16* w2h = (u16*)alloc((size_t)N1 * NIN * sizeof(u16));
    u16* w2l = (u16*)alloc((size_t)N1 * NIN * sizeof(u16));
    u16* dh  = (u16*)alloc((size_t)BATCH * NIN * sizeof(u16));
    u16* dl  = (u16*)alloc((size_t)BATCH * NIN * sizeof(u16));
    float* partial = (float*)alloc((size_t)4 * BATCH * N1 * sizeof(float));
    float* inp1 = (float*)alloc((size_t)BATCH * N1 * sizeof(float));
    float* s0f[2], *s1f[2];
    u16 *s0h[2], *s0l[2], *s1h[2], *s1l[2];
    for (int i = 0; i < 2; ++i) {
        s0f[i] = (float*)alloc((size_t)BATCH * N0 * sizeof(float));
        s1f[i] = (float*)alloc((size_t)BATCH * N1 * sizeof(float));
        s0h[i] = (u16*)alloc((size_t)BATCH * N0 * sizeof(u16));
        s0l[i] = (u16*)alloc((size_t)BATCH * N0 * sizeof(u16));
        s1h[i] = (u16*)alloc((size_t)BATCH * N1 * sizeof(u16));
        s1l[i] = (u16*)alloc((size_t)BATCH * N1 * sizeof(u16));
    }

    prep_kernel<<<2048, 256, 0, stream>>>(w0, w1, w2, data, s0_0, s1_0,
                                          w0h, w0l, w1h, w1l, w2h, w2l, dh, dl,
                                          s0f[0], s1f[0], s0h[0], s0l[0], s1h[0], s1l[0]);

    inp1_kernel<<<512, 512, 0, stream>>>(dh, dl, w2h, w2l, partial);
    reduce_kernel<<<BATCH * N1 / 4 / 256, 256, 0, stream>>>(partial, b2, inp1);

    float* out_s0 = (float*)d_out;
    float* out_s1 = (float*)d_out + (size_t)BATCH * N0;

    for (int t = 0; t < TSTEPS; ++t) {
        const int cur = t & 1, nxt = cur ^ 1;
        float* s0o = (t == TSTEPS - 1) ? out_s0 : s0f[nxt];
        float* s1o = (t == TSTEPS - 1) ? out_s1 : s1f[nxt];
        step_kernel<<<256, 512, 0, stream>>>(
            s0f[cur], s1f[cur],
            s0h[cur], s0l[cur], s1h[cur], s1l[cur],
            w0h, w0l, w1h, w1l,
            inp1, b0,
            s0o, s1o,
            s0h[nxt], s0l[nxt], s1h[nxt], s1l[nxt]);
    }
}